// Round 1
// baseline (852.731 us; speedup 1.0000x reference)
//
#include <hip/hip_runtime.h>

typedef __attribute__((ext_vector_type(8))) _Float16 half8;
typedef __attribute__((ext_vector_type(4))) float floatx4;
typedef unsigned short us_t;

#define SEQ   2048
#define DIN   4096
#define NOUT  11008
#define KTOK  2201
#define NCORE 4403
#define NCHUNK 43   /* NOUT / 256 */
#define NBLK  1376  /* (NOUT/128) * (SEQ/128) = 86 * 16, divisible by 8 XCDs */

__device__ __forceinline__ unsigned pk2(float a, float b) {
  auto h = __builtin_amdgcn_cvt_pkrtz(a, b);  // exact: values are f16-origin
  return __builtin_bit_cast(unsigned, h);
}
// monotone map: f32 bits -> ascending-ordered u32 key
__device__ __forceinline__ unsigned fkey32(unsigned u) {
  return u ^ ((u >> 31) ? 0xFFFFFFFFu : 0x80000000u);
}
__device__ __forceinline__ void gl2lds16(const us_t* g, us_t* l) {
  __builtin_amdgcn_global_load_lds(
      (const __attribute__((address_space(1))) unsigned int*)(g),
      (__attribute__((address_space(3))) unsigned int*)(l), 16, 0, 0);
}

// ---------------- f32 -> f16 conversion (8 elems/thread) ----------------
__global__ __launch_bounds__(256) void cvt_f16(const float* __restrict__ src,
                                               unsigned* __restrict__ dst, int n8) {
  int i = blockIdx.x * 256 + threadIdx.x;
  if (i >= n8) return;
  const float4* s = (const float4*)src + (size_t)i * 2;
  float4 a = s[0], b = s[1];
  uint4 o = {pk2(a.x, a.y), pk2(a.z, a.w), pk2(b.x, b.y), pk2(b.z, b.w)};
  ((uint4*)dst)[i] = o;
}

// ---------------- fast GEMM: f16 via global_load_lds, counted-vmcnt pipeline ----------
// Structure change vs prior round: double-buffered LDS K-tiles, prefetch
// distance 2 (8 global_load_lds in flight), raw s_barrier + inline-asm
// s_waitcnt vmcnt(4) so next tile's loads stay in flight across barriers
// (T3+T4 minimum form). sched_barrier(0) fences pin ds_read/MFMA inside
// their phase (rule #18). Grid is 1D with bijective XCD-chunked swizzle:
// each XCD owns 2 m-rows (2MB of A -> L2-resident), streams B.
__global__ __launch_bounds__(256) void gemm_f16(const us_t* __restrict__ X16,
                                                const us_t* __restrict__ W16,
                                                const float* __restrict__ Bias,
                                                float* __restrict__ C) {
  __shared__ __attribute__((aligned(16))) us_t As[2][128 * 32];
  __shared__ __attribute__((aligned(16))) us_t Bs[2][128 * 32];
  const int t = threadIdx.x;

  // XCD-chunked bijection: id%8 -> XCD; each XCD gets 172 consecutive wg
  // = 2 full m-rows (all 86 n). 1376 % 8 == 0 so this is exact.
  const int id = blockIdx.x;
  const int wg = ((id & 7) * (NBLK / 8)) + (id >> 3);
  const int m0 = (wg / 86) * 128;
  const int n0 = (wg % 86) * 128;

  const int l = t & 63, w = t >> 6;
  const int r = l & 15, q = l >> 4;
  const int wm = (w >> 1) * 64, wn = (w & 1) * 64;

  const us_t* Ag = X16 + (size_t)(m0 + (t >> 2)) * DIN + (t & 3) * 8;
  const us_t* Bg = W16 + (size_t)(n0 + (t >> 2)) * DIN + (t & 3) * 8;
  us_t* la0 = &As[0][t * 8];
  us_t* la1 = &As[1][t * 8];
  us_t* lb0 = &Bs[0][t * 8];
  us_t* lb1 = &Bs[1][t * 8];

  floatx4 acc[4][4] = {};
  const us_t* pa0 = &As[0][(wm + r) * 32 + q * 8];
  const us_t* pa1 = &As[1][(wm + r) * 32 + q * 8];
  const us_t* pb0 = &Bs[0][(wm + r) * 32 + q * 8]; // note: wn used below via pb base
  const us_t* pb0n = &Bs[0][(wn + r) * 32 + q * 8];
  const us_t* pb1n = &Bs[1][(wn + r) * 32 + q * 8];
  (void)pb0;

  auto stage = [&](us_t* la_, us_t* lb_, int kt) {
    gl2lds16(Ag + kt, la_);
    gl2lds16(Ag + kt + 64 * DIN, la_ + 2048);
    gl2lds16(Bg + kt, lb_);
    gl2lds16(Bg + kt + 64 * DIN, lb_ + 2048);
  };
  auto compute = [&](const us_t* pa_, const us_t* pb_) {
    half8 af[4];
#pragma unroll
    for (int im = 0; im < 4; ++im)
      af[im] = *(const half8*)(pa_ + im * 16 * 32);
#pragma unroll
    for (int in = 0; in < 4; ++in) {
      half8 bfv = *(const half8*)(pb_ + in * 16 * 32);
#pragma unroll
      for (int im = 0; im < 4; ++im)
        acc[im][in] = __builtin_amdgcn_mfma_f32_16x16x32_f16(af[im], bfv, acc[im][in], 0, 0, 0);
    }
  };

  // prologue: tiles 0 (buf0) and 32 (buf1) in flight -> vmcnt outstanding = 8
  stage(la0, lb0, 0);
  stage(la1, lb1, 32);

  for (int kt = 0; kt < DIN - 64; kt += 64) {
    // tile kt (buf0): wait its 4 loads (next tile's 4 stay in flight)
    asm volatile("s_waitcnt vmcnt(4)" ::: "memory");
    __builtin_amdgcn_s_barrier();
    __builtin_amdgcn_sched_barrier(0);
    compute(pa0, pb0n);
    __builtin_amdgcn_sched_barrier(0);
    __builtin_amdgcn_s_barrier();   // everyone done reading buf0
    __builtin_amdgcn_sched_barrier(0);
    stage(la0, lb0, kt + 64);       // refill buf0 with tile kt+64

    // tile kt+32 (buf1)
    asm volatile("s_waitcnt vmcnt(4)" ::: "memory");
    __builtin_amdgcn_s_barrier();
    __builtin_amdgcn_sched_barrier(0);
    compute(pa1, pb1n);
    __builtin_amdgcn_sched_barrier(0);
    __builtin_amdgcn_s_barrier();   // everyone done reading buf1
    __builtin_amdgcn_sched_barrier(0);
    stage(la1, lb1, kt + 96);       // refill buf1 with tile kt+96
  }
  // tail: tiles DIN-64 (buf0) and DIN-32 (buf1), nothing left to stage
  asm volatile("s_waitcnt vmcnt(4)" ::: "memory");
  __builtin_amdgcn_s_barrier();
  __builtin_amdgcn_sched_barrier(0);
  compute(pa0, pb0n);
  __builtin_amdgcn_sched_barrier(0);
  asm volatile("s_waitcnt vmcnt(0)" ::: "memory");
  __builtin_amdgcn_s_barrier();
  __builtin_amdgcn_sched_barrier(0);
  compute(pa1, pb1n);

#pragma unroll
  for (int in = 0; in < 4; ++in) {
    const int col = n0 + wn + in * 16 + r;
    const float bv = Bias[col];
#pragma unroll
    for (int im = 0; im < 4; ++im) {
      const int row = m0 + wm + im * 16 + q * 4;
#pragma unroll
      for (int i = 0; i < 4; ++i)
        C[(size_t)(row + i) * NOUT + col] = acc[im][in][i] + bv;
    }
  }
}

// ---------------- fallback GEMM (f32 staging, round-4 verified) ----------------
__global__ __launch_bounds__(256) void gemm_bias(const float* __restrict__ X,
                                                 const float* __restrict__ W,
                                                 const float* __restrict__ Bias,
                                                 float* __restrict__ C) {
  __shared__ __attribute__((aligned(16))) us_t As[128 * 32];
  __shared__ __attribute__((aligned(16))) us_t Bs[128 * 32];
  const int t = threadIdx.x;
  const int m0 = blockIdx.y * 128, n0 = blockIdx.x * 128;
  const int l = t & 63, w = t >> 6;
  const int r = l & 15, q = l >> 4;
  const int wm = (w >> 1) * 64, wn = (w & 1) * 64;
  const float* Ag = X + (size_t)(m0 + (t >> 2)) * DIN + (t & 3) * 8;
  const float* Bg = W + (size_t)(n0 + (t >> 2)) * DIN + (t & 3) * 8;
  us_t* la = As + t * 8;
  us_t* lb = Bs + t * 8;
  floatx4 acc[4][4] = {};
  const us_t* pa = As + (wm + r) * 32 + q * 8;
  const us_t* pb = Bs + (wn + r) * 32 + q * 8;
  for (int kt = 0; kt < DIN; kt += 32) {
    float4 a0 = *(const float4*)(Ag + kt);
    float4 a1 = *(const float4*)(Ag + kt + 4);
    float4 a2 = *(const float4*)(Ag + kt + 64 * DIN);
    float4 a3 = *(const float4*)(Ag + kt + 64 * DIN + 4);
    float4 b0 = *(const float4*)(Bg + kt);
    float4 b1 = *(const float4*)(Bg + kt + 4);
    float4 b2 = *(const float4*)(Bg + kt + 64 * DIN);
    float4 b3 = *(const float4*)(Bg + kt + 64 * DIN + 4);
    uint4 ua  = {pk2(a0.x, a0.y), pk2(a0.z, a0.w), pk2(a1.x, a1.y), pk2(a1.z, a1.w)};
    uint4 ua2 = {pk2(a2.x, a2.y), pk2(a2.z, a2.w), pk2(a3.x, a3.y), pk2(a3.z, a3.w)};
    uint4 ub  = {pk2(b0.x, b0.y), pk2(b0.z, b0.w), pk2(b1.x, b1.y), pk2(b1.z, b1.w)};
    uint4 ub2 = {pk2(b2.x, b2.y), pk2(b2.z, b2.w), pk2(b3.x, b3.y), pk2(b3.z, b3.w)};
    *(uint4*)la = ua;
    *(uint4*)(la + 2048) = ua2;
    *(uint4*)lb = ub;
    *(uint4*)(lb + 2048) = ub2;
    __syncthreads();
    half8 af[4];
#pragma unroll
    for (int im = 0; im < 4; ++im)
      af[im] = *(const half8*)(pa + im * 16 * 32);
#pragma unroll
    for (int in = 0; in < 4; ++in) {
      half8 bfv = *(const half8*)(pb + in * 16 * 32);
#pragma unroll
      for (int im = 0; im < 4; ++im)
        acc[im][in] = __builtin_amdgcn_mfma_f32_16x16x32_f16(af[im], bfv, acc[im][in], 0, 0, 0);
    }
    __syncthreads();
  }
#pragma unroll
  for (int in = 0; in < 4; ++in) {
    const int col = n0 + wn + in * 16 + r;
    const float bv = Bias[col];
#pragma unroll
    for (int im = 0; im < 4; ++im) {
      const int row = m0 + wm + im * 16 + q * 4;
#pragma unroll
      for (int i = 0; i < 4; ++i)
        C[(size_t)(row + i) * NOUT + col] = acc[im][in][i] + bv;
    }
  }
}

// ---------------- per-row exact top-KTOK membership -> counts ----------------
__global__ __launch_bounds__(256) void row_topk(const float* __restrict__ TV,
                                                int* __restrict__ counts) {
  __shared__ __attribute__((aligned(16))) unsigned keys[NOUT];
  __shared__ int hist[2048];
  __shared__ int csum[256];
  __shared__ int shv[2];
  __shared__ int cnte[NCHUNK * 4];
  const int t = threadIdx.x;
  const int lane = t & 63, wv = t >> 6;

  for (int i = t; i < 2048; i += 256) hist[i] = 0;
  __syncthreads();
  // fused: load + key + pass-A histogram (bits [31:21])
  const uint4* src = (const uint4*)(TV + (size_t)blockIdx.x * NOUT);
  for (int i = t; i < NOUT / 4; i += 256) {
    uint4 v = src[i];
    unsigned k0 = fkey32(v.x), k1 = fkey32(v.y), k2 = fkey32(v.z), k3 = fkey32(v.w);
    uint4 kk = {k0, k1, k2, k3};
    *(uint4*)&keys[i * 4] = kk;
    atomicAdd(&hist[k0 >> 21], 1);
    atomicAdd(&hist[k1 >> 21], 1);
    atomicAdd(&hist[k2 >> 21], 1);
    atomicAdd(&hist[k3 >> 21], 1);
  }
  __syncthreads();
  { int s = 0; for (int j = 0; j < 8; ++j) s += hist[t * 8 + j]; csum[t] = s; }
  __syncthreads();
  if (t == 0) {
    int cum = 0;
    for (int c = 255; c >= 0; --c) {
      if (cum + csum[c] >= KTOK) {
        for (int v = c * 8 + 7; v >= c * 8; --v) {
          if (cum + hist[v] >= KTOK) { shv[0] = v; shv[1] = cum; break; }
          cum += hist[v];
        }
        break;
      }
      cum += csum[c];
    }
  }
  __syncthreads();
  const unsigned b1 = (unsigned)shv[0];
  const int above1 = shv[1];
  __syncthreads();

  // pass B: bits [20:10] among prefix==b1
  for (int i = t; i < 2048; i += 256) hist[i] = 0;
  __syncthreads();
  for (int i = t; i < NOUT; i += 256) {
    unsigned k = keys[i];
    if ((k >> 21) == b1) atomicAdd(&hist[(k >> 10) & 0x7FF], 1);
  }
  __syncthreads();
  { int s = 0; for (int j = 0; j < 8; ++j) s += hist[t * 8 + j]; csum[t] = s; }
  __syncthreads();
  if (t == 0) {
    int cum = above1;
    for (int c = 255; c >= 0; --c) {
      if (cum + csum[c] >= KTOK) {
        for (int v = c * 8 + 7; v >= c * 8; --v) {
          if (cum + hist[v] >= KTOK) { shv[0] = v; shv[1] = cum; break; }
          cum += hist[v];
        }
        break;
      }
      cum += csum[c];
    }
  }
  __syncthreads();
  const unsigned b2 = (unsigned)shv[0];
  const int above2 = shv[1];
  const unsigned pref2 = (b1 << 11) | b2;
  __syncthreads();

  // pass C: bits [9:0] among prefix==pref2
  for (int i = t; i < 1024; i += 256) hist[i] = 0;
  __syncthreads();
  for (int i = t; i < NOUT; i += 256) {
    unsigned k = keys[i];
    if ((k >> 10) == pref2) atomicAdd(&hist[k & 0x3FF], 1);
  }
  __syncthreads();
  { int s = 0; if (t < 128) { for (int j = 0; j < 8; ++j) s += hist[t * 8 + j]; } csum[t] = s; }
  __syncthreads();
  if (t == 0) {
    int cum = above2;
    for (int c = 127; c >= 0; --c) {
      if (cum + csum[c] >= KTOK) {
        for (int v = c * 8 + 7; v >= c * 8; --v) {
          if (cum + hist[v] >= KTOK) { shv[0] = v; shv[1] = cum; break; }
          cum += hist[v];
        }
        break;
      }
      cum += csum[c];
    }
  }
  __syncthreads();
  const unsigned T = (pref2 << 10) | (unsigned)shv[0];
  const int need = KTOK - shv[1];  // ties at T: ascending index order

  // membership sweep 1 (barrier-free): gt adds + per-(chunk,wave) eq counts
  for (int c = 0; c < NCHUNK; ++c) {
    const int i = c * 256 + t;
    const unsigned k = keys[i];
    if (k > T) atomicAdd(&counts[i], 1);
    unsigned long long me = __ballot(k == T);
    if (lane == 0) cnte[c * 4 + wv] = __popcll(me);
  }
  __syncthreads();
  // sweep 2: eq-rank resolution (eq elements rare; prefix computed on demand)
  for (int c = 0; c < NCHUNK; ++c) {
    const int i = c * 256 + t;
    const unsigned k = keys[i];
    const bool eq = (k == T);
    unsigned long long me = __ballot(eq);
    if (eq) {
      int rank = __popcll(me & ((1ULL << lane) - 1));
      const int idx = c * 4 + wv;
      for (int j = 0; j < idx; ++j) rank += cnte[j];
      if (rank < need) atomicAdd(&counts[i], 1);
    }
  }
}

// ---------------- top-NCORE of counts (ties: lower index), emit in index order --------
__global__ __launch_bounds__(256) void select_core(const int* __restrict__ counts,
                                                   const float* __restrict__ Bias,
                                                   int* __restrict__ core_idx,
                                                   float* __restrict__ bias_out) {
  __shared__ int cl[NOUT];
  __shared__ int hist[2049];
  __shared__ int csum[257];
  __shared__ int shv[2];
  __shared__ int tabS[256];  // packed (gt | eq<<16) per (chunk,wave)
  const int t = threadIdx.x;
  const int lane = t & 63, wv = t >> 6;
  for (int i = t; i < NOUT; i += 256) cl[i] = counts[i];
  for (int i = t; i < 2049; i += 256) hist[i] = 0;
  tabS[t] = 0;
  __syncthreads();
  for (int i = t; i < NOUT; i += 256) atomicAdd(&hist[cl[i]], 1);
  __syncthreads();
  { int s = 0; for (int j = 0; j < 8; ++j) s += hist[t * 8 + j]; csum[t] = s;
    if (t == 0) csum[256] = hist[2048]; }
  __syncthreads();
  if (t == 0) {
    int cum = 0;
    for (int c = 256; c >= 0; --c) {
      if (cum + csum[c] >= NCORE) {
        int hi = (c == 256) ? 2048 : c * 8 + 7;
        for (int v = hi; v >= c * 8; --v) {
          if (cum + hist[v] >= NCORE) { shv[0] = v; shv[1] = NCORE - cum; break; }
          cum += hist[v];
        }
        break;
      }
      cum += csum[c];
    }
  }
  __syncthreads();
  const int Cv = shv[0], need2 = shv[1];
  // sweep 1: per-(chunk,wave) ballot counts (no barriers)
  for (int c = 0; c < NCHUNK; ++c) {
    const int i = c * 256 + t;
    const int cnt = cl[i];
    unsigned long long mg = __ballot(cnt > Cv);
    unsigned long long me = __ballot(cnt == Cv);
    if (lane == 0) tabS[c * 4 + wv] = __popcll(mg) | (__popcll(me) << 16);
  }
  __syncthreads();
  // packed inclusive Hillis-Steele scan -> exclusive prefix
  int orig = tabS[t];
  for (int off = 1; off < 256; off <<= 1) {
    int v = (t >= off) ? tabS[t - off] : 0;
    __syncthreads();
    tabS[t] += v;
    __syncthreads();
  }
  int excl = tabS[t] - orig;
  __syncthreads();
  tabS[t] = excl;
  __syncthreads();
  // sweep 2: compute position, emit
  const unsigned long long lm = (1ULL << lane) - 1;
  for (int c = 0; c < NCHUNK; ++c) {
    const int i = c * 256 + t;
    const int cnt = cl[i];
    const bool g = cnt > Cv, e = cnt == Cv;
    unsigned long long mg = __ballot(g);
    unsigned long long me = __ballot(e);
    const int P = tabS[c * 4 + wv];
    const int gpre = (P & 0xFFFF) + __popcll(mg & lm);
    const int epre = (P >> 16) + __popcll(me & lm);
    const bool sel = g || (e && epre < need2);
    if (sel) {
      const int pos = gpre + (epre < need2 ? epre : need2);
      core_idx[pos] = i;
      bias_out[pos] = Bias[i];
    }
  }
}

// ---------------- gather selected weight rows (f32) ----------------
__global__ __launch_bounds__(256) void gather_rows(const float* __restrict__ W,
                                                   const int* __restrict__ core_idx,
                                                   float* __restrict__ outW) {
  const int b = blockIdx.x;
  const int j = core_idx[b];
  const float4* src = (const float4*)(W + (size_t)j * DIN);
  float4* dst = (float4*)(outW + (size_t)b * DIN);
  for (int i = threadIdx.x; i < DIN / 4; i += 256) dst[i] = src[i];
}

__global__ __launch_bounds__(256) void zero_counts(int* __restrict__ counts) {
  counts[blockIdx.x * 256 + threadIdx.x] = 0;
}

extern "C" void kernel_launch(void* const* d_in, const int* in_sizes, int n_in,
                              void* d_out, int out_size, void* d_ws, size_t ws_size,
                              hipStream_t stream) {
  const float* X    = (const float*)d_in[0];
  const float* W    = (const float*)d_in[1];
  const float* Bias = (const float*)d_in[2];
  float* out_tv = (float*)d_out;
  float* out_w  = out_tv + (size_t)SEQ * NOUT;
  float* out_b  = out_w + (size_t)NCORE * DIN;
  int* counts   = (int*)d_ws;
  int* core_idx = counts + NOUT;

  const size_t meta = 64 * 1024;
  const size_t need_ws = meta + ((size_t)SEQ * DIN + (size_t)NOUT * DIN) * sizeof(us_t);

  zero_counts<<<NOUT / 256, 256, 0, stream>>>(counts);
  if (ws_size >= need_ws) {
    us_t* X16 = (us_t*)((char*)d_ws + meta);
    us_t* W16 = X16 + (size_t)SEQ * DIN;
    cvt_f16<<<(SEQ * DIN / 8 + 255) / 256, 256, 0, stream>>>(X, (unsigned*)X16, SEQ * DIN / 8);
    cvt_f16<<<(NOUT * DIN / 8 + 255) / 256, 256, 0, stream>>>(W, (unsigned*)W16, NOUT * DIN / 8);
    gemm_f16<<<NBLK, 256, 0, stream>>>(X16, W16, Bias, out_tv);
  } else {
    gemm_bias<<<dim3(NOUT / 128, SEQ / 128), 256, 0, stream>>>(X, W, Bias, out_tv);
  }
  row_topk<<<SEQ, 256, 0, stream>>>(out_tv, counts);
  select_core<<<1, 256, 0, stream>>>(counts, Bias, core_idx, out_b);
  gather_rows<<<NCORE, 256, 0, stream>>>(W, core_idx, out_w);
}

// Round 2
// 749.359 us; speedup vs baseline: 1.1379x; 1.1379x over previous
//
#include <hip/hip_runtime.h>

typedef __attribute__((ext_vector_type(8))) _Float16 half8;
typedef __attribute__((ext_vector_type(4))) float floatx4;
typedef unsigned short us_t;

#define SEQ   2048
#define DIN   4096
#define NOUT  11008
#define KTOK  2201
#define NCORE 4403
#define NCHUNK 43   /* NOUT / 256 */
#define NBLK  1376  /* (NOUT/128) * (SEQ/128) = 86 * 16, divisible by 8 XCDs */

__device__ __forceinline__ unsigned pk2(float a, float b) {
  auto h = __builtin_amdgcn_cvt_pkrtz(a, b);  // exact: values are f16-origin
  return __builtin_bit_cast(unsigned, h);
}
// monotone map: f32 bits -> ascending-ordered u32 key
__device__ __forceinline__ unsigned fkey32(unsigned u) {
  return u ^ ((u >> 31) ? 0xFFFFFFFFu : 0x80000000u);
}
__device__ __forceinline__ void gl2lds16(const us_t* g, us_t* l) {
  __builtin_amdgcn_global_load_lds(
      (const __attribute__((address_space(1))) unsigned int*)(g),
      (__attribute__((address_space(3))) unsigned int*)(l), 16, 0, 0);
}

// ---------------- f32 -> f16 conversion (8 elems/thread) ----------------
__global__ __launch_bounds__(256) void cvt_f16(const float* __restrict__ src,
                                               unsigned* __restrict__ dst, int n8) {
  int i = blockIdx.x * 256 + threadIdx.x;
  if (i >= n8) return;
  const float4* s = (const float4*)src + (size_t)i * 2;
  float4 a = s[0], b = s[1];
  uint4 o = {pk2(a.x, a.y), pk2(a.z, a.w), pk2(b.x, b.y), pk2(b.z, b.w)};
  ((uint4*)dst)[i] = o;
}

// ---------------- fast GEMM: f16 inputs via global_load_lds (m97 structure) ----------
// Round-2 change vs round-0: 1D grid + n-major block order + bijective
// XCD-chunk swizzle. Co-resident blocks now share W-panels (16 m-tiles of
// one n-column run together -> each 1MB W panel fetched from HBM ~once,
// resident W footprint ~39MB + X 17MB << L3). Round-1's counted-vmcnt
// double-buffer REVERTED (regressed: occupancy loss + sched_barrier
// pinning, per-guide regime gate for 128^2 2-phase).
__global__ __launch_bounds__(256) void gemm_f16(const us_t* __restrict__ X16,
                                                const us_t* __restrict__ W16,
                                                const float* __restrict__ Bias,
                                                float* __restrict__ C) {
  __shared__ __attribute__((aligned(16))) us_t As[128 * 32];
  __shared__ __attribute__((aligned(16))) us_t Bs[128 * 32];
  const int t = threadIdx.x;

  // bijective XCD-chunk swizzle (1376 = 8 * 172): id%8 -> XCD, each XCD
  // gets 172 consecutive wg of the n-major sequence.
  const int id = blockIdx.x;
  const int wg = ((id & 7) * (NBLK / 8)) + (id >> 3);
  const int n0 = (wg >> 4) * 128;  // n-major: column advances every 16 wg
  const int m0 = (wg & 15) * 128;  // 16 m-tiles of one column are consecutive

  const int l = t & 63, w = t >> 6;
  const int r = l & 15, q = l >> 4;
  const int wm = (w >> 1) * 64, wn = (w & 1) * 64;

  const us_t* Ag = X16 + (size_t)(m0 + (t >> 2)) * DIN + (t & 3) * 8;
  const us_t* Bg = W16 + (size_t)(n0 + (t >> 2)) * DIN + (t & 3) * 8;
  us_t* la = As + t * 8;
  us_t* lb = Bs + t * 8;

  floatx4 acc[4][4] = {};
  const us_t* pa = As + (wm + r) * 32 + q * 8;
  const us_t* pb = Bs + (wn + r) * 32 + q * 8;

  for (int kt = 0; kt < DIN; kt += 32) {
    gl2lds16(Ag + kt, la);
    gl2lds16(Ag + kt + 64 * DIN, la + 2048);
    gl2lds16(Bg + kt, lb);
    gl2lds16(Bg + kt + 64 * DIN, lb + 2048);
    __syncthreads();
    half8 af[4];
#pragma unroll
    for (int im = 0; im < 4; ++im)
      af[im] = *(const half8*)(pa + im * 16 * 32);
#pragma unroll
    for (int in = 0; in < 4; ++in) {
      half8 bfv = *(const half8*)(pb + in * 16 * 32);
#pragma unroll
      for (int im = 0; im < 4; ++im)
        acc[im][in] = __builtin_amdgcn_mfma_f32_16x16x32_f16(af[im], bfv, acc[im][in], 0, 0, 0);
    }
    __syncthreads();
  }
#pragma unroll
  for (int in = 0; in < 4; ++in) {
    const int col = n0 + wn + in * 16 + r;
    const float bv = Bias[col];
#pragma unroll
    for (int im = 0; im < 4; ++im) {
      const int row = m0 + wm + im * 16 + q * 4;
#pragma unroll
      for (int i = 0; i < 4; ++i)
        C[(size_t)(row + i) * NOUT + col] = acc[im][in][i] + bv;
    }
  }
}

// ---------------- fallback GEMM (f32 staging, round-4 verified) ----------------
__global__ __launch_bounds__(256) void gemm_bias(const float* __restrict__ X,
                                                 const float* __restrict__ W,
                                                 const float* __restrict__ Bias,
                                                 float* __restrict__ C) {
  __shared__ __attribute__((aligned(16))) us_t As[128 * 32];
  __shared__ __attribute__((aligned(16))) us_t Bs[128 * 32];
  const int t = threadIdx.x;
  const int m0 = blockIdx.y * 128, n0 = blockIdx.x * 128;
  const int l = t & 63, w = t >> 6;
  const int r = l & 15, q = l >> 4;
  const int wm = (w >> 1) * 64, wn = (w & 1) * 64;
  const float* Ag = X + (size_t)(m0 + (t >> 2)) * DIN + (t & 3) * 8;
  const float* Bg = W + (size_t)(n0 + (t >> 2)) * DIN + (t & 3) * 8;
  us_t* la = As + t * 8;
  us_t* lb = Bs + t * 8;
  floatx4 acc[4][4] = {};
  const us_t* pa = As + (wm + r) * 32 + q * 8;
  const us_t* pb = Bs + (wn + r) * 32 + q * 8;
  for (int kt = 0; kt < DIN; kt += 32) {
    float4 a0 = *(const float4*)(Ag + kt);
    float4 a1 = *(const float4*)(Ag + kt + 4);
    float4 a2 = *(const float4*)(Ag + kt + 64 * DIN);
    float4 a3 = *(const float4*)(Ag + kt + 64 * DIN + 4);
    float4 b0 = *(const float4*)(Bg + kt);
    float4 b1 = *(const float4*)(Bg + kt + 4);
    float4 b2 = *(const float4*)(Bg + kt + 64 * DIN);
    float4 b3 = *(const float4*)(Bg + kt + 64 * DIN + 4);
    uint4 ua  = {pk2(a0.x, a0.y), pk2(a0.z, a0.w), pk2(a1.x, a1.y), pk2(a1.z, a1.w)};
    uint4 ua2 = {pk2(a2.x, a2.y), pk2(a2.z, a2.w), pk2(a3.x, a3.y), pk2(a3.z, a3.w)};
    uint4 ub  = {pk2(b0.x, b0.y), pk2(b0.z, b0.w), pk2(b1.x, b1.y), pk2(b1.z, b1.w)};
    uint4 ub2 = {pk2(b2.x, b2.y), pk2(b2.z, b2.w), pk2(b3.x, b3.y), pk2(b3.z, b3.w)};
    *(uint4*)la = ua;
    *(uint4*)(la + 2048) = ua2;
    *(uint4*)lb = ub;
    *(uint4*)(lb + 2048) = ub2;
    __syncthreads();
    half8 af[4];
#pragma unroll
    for (int im = 0; im < 4; ++im)
      af[im] = *(const half8*)(pa + im * 16 * 32);
#pragma unroll
    for (int in = 0; in < 4; ++in) {
      half8 bfv = *(const half8*)(pb + in * 16 * 32);
#pragma unroll
      for (int im = 0; im < 4; ++im)
        acc[im][in] = __builtin_amdgcn_mfma_f32_16x16x32_f16(af[im], bfv, acc[im][in], 0, 0, 0);
    }
    __syncthreads();
  }
#pragma unroll
  for (int in = 0; in < 4; ++in) {
    const int col = n0 + wn + in * 16 + r;
    const float bv = Bias[col];
#pragma unroll
    for (int im = 0; im < 4; ++im) {
      const int row = m0 + wm + im * 16 + q * 4;
#pragma unroll
      for (int i = 0; i < 4; ++i)
        C[(size_t)(row + i) * NOUT + col] = acc[im][in][i] + bv;
    }
  }
}

// ---------------- per-row exact top-KTOK membership -> counts ----------------
__global__ __launch_bounds__(256) void row_topk(const float* __restrict__ TV,
                                                int* __restrict__ counts) {
  __shared__ __attribute__((aligned(16))) unsigned keys[NOUT];
  __shared__ int hist[2048];
  __shared__ int csum[256];
  __shared__ int shv[2];
  __shared__ int cnte[NCHUNK * 4];
  const int t = threadIdx.x;
  const int lane = t & 63, wv = t >> 6;

  for (int i = t; i < 2048; i += 256) hist[i] = 0;
  __syncthreads();
  // fused: load + key + pass-A histogram (bits [31:21])
  const uint4* src = (const uint4*)(TV + (size_t)blockIdx.x * NOUT);
  for (int i = t; i < NOUT / 4; i += 256) {
    uint4 v = src[i];
    unsigned k0 = fkey32(v.x), k1 = fkey32(v.y), k2 = fkey32(v.z), k3 = fkey32(v.w);
    uint4 kk = {k0, k1, k2, k3};
    *(uint4*)&keys[i * 4] = kk;
    atomicAdd(&hist[k0 >> 21], 1);
    atomicAdd(&hist[k1 >> 21], 1);
    atomicAdd(&hist[k2 >> 21], 1);
    atomicAdd(&hist[k3 >> 21], 1);
  }
  __syncthreads();
  { int s = 0; for (int j = 0; j < 8; ++j) s += hist[t * 8 + j]; csum[t] = s; }
  __syncthreads();
  if (t == 0) {
    int cum = 0;
    for (int c = 255; c >= 0; --c) {
      if (cum + csum[c] >= KTOK) {
        for (int v = c * 8 + 7; v >= c * 8; --v) {
          if (cum + hist[v] >= KTOK) { shv[0] = v; shv[1] = cum; break; }
          cum += hist[v];
        }
        break;
      }
      cum += csum[c];
    }
  }
  __syncthreads();
  const unsigned b1 = (unsigned)shv[0];
  const int above1 = shv[1];
  __syncthreads();

  // pass B: bits [20:10] among prefix==b1
  for (int i = t; i < 2048; i += 256) hist[i] = 0;
  __syncthreads();
  for (int i = t; i < NOUT; i += 256) {
    unsigned k = keys[i];
    if ((k >> 21) == b1) atomicAdd(&hist[(k >> 10) & 0x7FF], 1);
  }
  __syncthreads();
  { int s = 0; for (int j = 0; j < 8; ++j) s += hist[t * 8 + j]; csum[t] = s; }
  __syncthreads();
  if (t == 0) {
    int cum = above1;
    for (int c = 255; c >= 0; --c) {
      if (cum + csum[c] >= KTOK) {
        for (int v = c * 8 + 7; v >= c * 8; --v) {
          if (cum + hist[v] >= KTOK) { shv[0] = v; shv[1] = cum; break; }
          cum += hist[v];
        }
        break;
      }
      cum += csum[c];
    }
  }
  __syncthreads();
  const unsigned b2 = (unsigned)shv[0];
  const int above2 = shv[1];
  const unsigned pref2 = (b1 << 11) | b2;
  __syncthreads();

  // pass C: bits [9:0] among prefix==pref2
  for (int i = t; i < 1024; i += 256) hist[i] = 0;
  __syncthreads();
  for (int i = t; i < NOUT; i += 256) {
    unsigned k = keys[i];
    if ((k >> 10) == pref2) atomicAdd(&hist[k & 0x3FF], 1);
  }
  __syncthreads();
  { int s = 0; if (t < 128) { for (int j = 0; j < 8; ++j) s += hist[t * 8 + j]; } csum[t] = s; }
  __syncthreads();
  if (t == 0) {
    int cum = above2;
    for (int c = 127; c >= 0; --c) {
      if (cum + csum[c] >= KTOK) {
        for (int v = c * 8 + 7; v >= c * 8; --v) {
          if (cum + hist[v] >= KTOK) { shv[0] = v; shv[1] = cum; break; }
          cum += hist[v];
        }
        break;
      }
      cum += csum[c];
    }
  }
  __syncthreads();
  const unsigned T = (pref2 << 10) | (unsigned)shv[0];
  const int need = KTOK - shv[1];  // ties at T: ascending index order

  // membership sweep 1 (barrier-free): gt adds + per-(chunk,wave) eq counts
  for (int c = 0; c < NCHUNK; ++c) {
    const int i = c * 256 + t;
    const unsigned k = keys[i];
    if (k > T) atomicAdd(&counts[i], 1);
    unsigned long long me = __ballot(k == T);
    if (lane == 0) cnte[c * 4 + wv] = __popcll(me);
  }
  __syncthreads();
  // sweep 2: eq-rank resolution (eq elements rare; prefix computed on demand)
  for (int c = 0; c < NCHUNK; ++c) {
    const int i = c * 256 + t;
    const unsigned k = keys[i];
    const bool eq = (k == T);
    unsigned long long me = __ballot(eq);
    if (eq) {
      int rank = __popcll(me & ((1ULL << lane) - 1));
      const int idx = c * 4 + wv;
      for (int j = 0; j < idx; ++j) rank += cnte[j];
      if (rank < need) atomicAdd(&counts[i], 1);
    }
  }
}

// ---------------- top-NCORE of counts (ties: lower index), emit in index order --------
__global__ __launch_bounds__(256) void select_core(const int* __restrict__ counts,
                                                   const float* __restrict__ Bias,
                                                   int* __restrict__ core_idx,
                                                   float* __restrict__ bias_out) {
  __shared__ int cl[NOUT];
  __shared__ int hist[2049];
  __shared__ int csum[257];
  __shared__ int shv[2];
  __shared__ int tabS[256];  // packed (gt | eq<<16) per (chunk,wave)
  const int t = threadIdx.x;
  const int lane = t & 63, wv = t >> 6;
  for (int i = t; i < NOUT; i += 256) cl[i] = counts[i];
  for (int i = t; i < 2049; i += 256) hist[i] = 0;
  tabS[t] = 0;
  __syncthreads();
  for (int i = t; i < NOUT; i += 256) atomicAdd(&hist[cl[i]], 1);
  __syncthreads();
  { int s = 0; for (int j = 0; j < 8; ++j) s += hist[t * 8 + j]; csum[t] = s;
    if (t == 0) csum[256] = hist[2048]; }
  __syncthreads();
  if (t == 0) {
    int cum = 0;
    for (int c = 256; c >= 0; --c) {
      if (cum + csum[c] >= NCORE) {
        int hi = (c == 256) ? 2048 : c * 8 + 7;
        for (int v = hi; v >= c * 8; --v) {
          if (cum + hist[v] >= NCORE) { shv[0] = v; shv[1] = NCORE - cum; break; }
          cum += hist[v];
        }
        break;
      }
      cum += csum[c];
    }
  }
  __syncthreads();
  const int Cv = shv[0], need2 = shv[1];
  // sweep 1: per-(chunk,wave) ballot counts (no barriers)
  for (int c = 0; c < NCHUNK; ++c) {
    const int i = c * 256 + t;
    const int cnt = cl[i];
    unsigned long long mg = __ballot(cnt > Cv);
    unsigned long long me = __ballot(cnt == Cv);
    if (lane == 0) tabS[c * 4 + wv] = __popcll(mg) | (__popcll(me) << 16);
  }
  __syncthreads();
  // packed inclusive Hillis-Steele scan -> exclusive prefix
  int orig = tabS[t];
  for (int off = 1; off < 256; off <<= 1) {
    int v = (t >= off) ? tabS[t - off] : 0;
    __syncthreads();
    tabS[t] += v;
    __syncthreads();
  }
  int excl = tabS[t] - orig;
  __syncthreads();
  tabS[t] = excl;
  __syncthreads();
  // sweep 2: compute position, emit
  const unsigned long long lm = (1ULL << lane) - 1;
  for (int c = 0; c < NCHUNK; ++c) {
    const int i = c * 256 + t;
    const int cnt = cl[i];
    const bool g = cnt > Cv, e = cnt == Cv;
    unsigned long long mg = __ballot(g);
    unsigned long long me = __ballot(e);
    const int P = tabS[c * 4 + wv];
    const int gpre = (P & 0xFFFF) + __popcll(mg & lm);
    const int epre = (P >> 16) + __popcll(me & lm);
    const bool sel = g || (e && epre < need2);
    if (sel) {
      const int pos = gpre + (epre < need2 ? epre : need2);
      core_idx[pos] = i;
      bias_out[pos] = Bias[i];
    }
  }
}

// ---------------- gather selected weight rows (f32) ----------------
__global__ __launch_bounds__(256) void gather_rows(const float* __restrict__ W,
                                                   const int* __restrict__ core_idx,
                                                   float* __restrict__ outW) {
  const int b = blockIdx.x;
  const int j = core_idx[b];
  const float4* src = (const float4*)(W + (size_t)j * DIN);
  float4* dst = (float4*)(outW + (size_t)b * DIN);
  for (int i = threadIdx.x; i < DIN / 4; i += 256) dst[i] = src[i];
}

__global__ __launch_bounds__(256) void zero_counts(int* __restrict__ counts) {
  counts[blockIdx.x * 256 + threadIdx.x] = 0;
}

extern "C" void kernel_launch(void* const* d_in, const int* in_sizes, int n_in,
                              void* d_out, int out_size, void* d_ws, size_t ws_size,
                              hipStream_t stream) {
  const float* X    = (const float*)d_in[0];
  const float* W    = (const float*)d_in[1];
  const float* Bias = (const float*)d_in[2];
  float* out_tv = (float*)d_out;
  float* out_w  = out_tv + (size_t)SEQ * NOUT;
  float* out_b  = out_w + (size_t)NCORE * DIN;
  int* counts   = (int*)d_ws;
  int* core_idx = counts + NOUT;

  const size_t meta = 64 * 1024;
  const size_t need_ws = meta + ((size_t)SEQ * DIN + (size_t)NOUT * DIN) * sizeof(us_t);

  zero_counts<<<NOUT / 256, 256, 0, stream>>>(counts);
  if (ws_size >= need_ws) {
    us_t* X16 = (us_t*)((char*)d_ws + meta);
    us_t* W16 = X16 + (size_t)SEQ * DIN;
    cvt_f16<<<(SEQ * DIN / 8 + 255) / 256, 256, 0, stream>>>(X, (unsigned*)X16, SEQ * DIN / 8);
    cvt_f16<<<(NOUT * DIN / 8 + 255) / 256, 256, 0, stream>>>(W, (unsigned*)W16, NOUT * DIN / 8);
    gemm_f16<<<NBLK, 256, 0, stream>>>(X16, W16, Bias, out_tv);
  } else {
    gemm_bias<<<dim3(NOUT / 128, SEQ / 128), 256, 0, stream>>>(X, W, Bias, out_tv);
  }
  row_topk<<<SEQ, 256, 0, stream>>>(out_tv, counts);
  select_core<<<1, 256, 0, stream>>>(counts, Bias, core_idx, out_b);
  gather_rows<<<NCORE, 256, 0, stream>>>(W, core_idx, out_w);
}

// Round 3
// 747.834 us; speedup vs baseline: 1.1403x; 1.0020x over previous
//
#include <hip/hip_runtime.h>

typedef __attribute__((ext_vector_type(8))) _Float16 half8;
typedef __attribute__((ext_vector_type(4))) float floatx4;
typedef unsigned short us_t;

#define SEQ   2048
#define DIN   4096
#define NOUT  11008
#define KTOK  2201
#define NCORE 4403
#define NCHUNK 43   /* NOUT / 256 */
#define NBLK  1376  /* (NOUT/128) * (SEQ/128) = 86 * 16, divisible by 8 XCDs */

__device__ __forceinline__ unsigned pk2(float a, float b) {
  auto h = __builtin_amdgcn_cvt_pkrtz(a, b);  // exact: values are f16-origin
  return __builtin_bit_cast(unsigned, h);
}
// monotone map: f32 bits -> ascending-ordered u32 key
__device__ __forceinline__ unsigned fkey32(unsigned u) {
  return u ^ ((u >> 31) ? 0xFFFFFFFFu : 0x80000000u);
}
__device__ __forceinline__ void gl2lds16(const us_t* g, us_t* l) {
  __builtin_amdgcn_global_load_lds(
      (const __attribute__((address_space(1))) unsigned int*)(g),
      (__attribute__((address_space(3))) unsigned int*)(l), 16, 0, 0);
}

// ---------------- f32 -> f16 conversion (8 elems/thread) ----------------
__global__ __launch_bounds__(256) void cvt_f16(const float* __restrict__ src,
                                               unsigned* __restrict__ dst, int n8) {
  int i = blockIdx.x * 256 + threadIdx.x;
  if (i >= n8) return;
  const float4* s = (const float4*)src + (size_t)i * 2;
  float4 a = s[0], b = s[1];
  uint4 o = {pk2(a.x, a.y), pk2(a.z, a.w), pk2(b.x, b.y), pk2(b.z, b.w)};
  ((uint4*)dst)[i] = o;
}

// ---------------- fast GEMM ----------------------------------------------------------
// Round-3: 128x128 tile, BK=64, LDS double-buffer, counted s_waitcnt vmcnt(8)
// across raw s_barrier (next K-tile's 8 global_load_lds stay in flight through
// the whole compute phase), T2 XOR-swizzle (inverse-swizzled GLOBAL source +
// swizzled ds_read, both-sides involution: physical chunk = logical ^ (row&7)),
// setprio around MFMA cluster. 64KB LDS -> 2 blocks/CU (keeps inter-block
// overlap). Grid order unchanged from round-2 (n-major + bijective XCD chunk).
__global__ __launch_bounds__(256) void gemm_f16(const us_t* __restrict__ X16,
                                                const us_t* __restrict__ W16,
                                                const float* __restrict__ Bias,
                                                float* __restrict__ C) {
  __shared__ __attribute__((aligned(16))) us_t As[2][128 * 64];
  __shared__ __attribute__((aligned(16))) us_t Bs[2][128 * 64];
  const int t = threadIdx.x;

  const int id = blockIdx.x;
  const int wg = ((id & 7) * (NBLK / 8)) + (id >> 3);
  const int n0 = (wg >> 4) * 128;  // n-major: 16 m-tiles per n-column, co-XCD
  const int m0 = (wg & 15) * 128;

  const int l = t & 63, w = t >> 6;
  const int r = l & 15, q = l >> 4, sw = l & 7;
  const int wm = (w >> 1) * 64, wn = (w & 1) * 64;

  // staging: issue covers 32 rows (256 thr x 16B); thread t -> row t>>3,
  // physical chunk t&7. Source fetches logical chunk (t&7)^(row&7) so that
  // linear gl2lds dest realizes the swizzled layout.
  const int tr = t >> 3;
  const int csw = ((t & 7) ^ (tr & 7)) * 8;
  const us_t* Ag = X16 + (size_t)(m0 + tr) * DIN + csw;
  const us_t* Bg = W16 + (size_t)(n0 + tr) * DIN + csw;

  floatx4 acc[4][4] = {};

  // fragment read: row*64 + ((ks*4+q) ^ (row&7))*8 ; row&7 == l&7
  const int s0 = (q ^ sw) * 8;
  const int s1 = ((4 + q) ^ sw) * 8;
  const int ra = (wm + r) * 64;
  const int rb = (wn + r) * 64;

#define STAGE8(bb, kt)                                                   \
  {                                                                      \
    const us_t* a_ = Ag + (kt);                                          \
    const us_t* b_ = Bg + (kt);                                          \
    us_t* la_ = &As[bb][t * 8];                                          \
    us_t* lb_ = &Bs[bb][t * 8];                                          \
    gl2lds16(a_, la_);                                                   \
    gl2lds16(a_ + 32 * DIN, la_ + 2048);                                 \
    gl2lds16(a_ + 64 * DIN, la_ + 4096);                                 \
    gl2lds16(a_ + 96 * DIN, la_ + 6144);                                 \
    gl2lds16(b_, lb_);                                                   \
    gl2lds16(b_ + 32 * DIN, lb_ + 2048);                                 \
    gl2lds16(b_ + 64 * DIN, lb_ + 4096);                                 \
    gl2lds16(b_ + 96 * DIN, lb_ + 6144);                                 \
  }

  STAGE8(0, 0);
  int buf = 0;
  for (int kt = 0; kt < DIN; kt += 64, buf ^= 1) {
    if (kt + 64 < DIN) {
      STAGE8(buf ^ 1, kt + 64);  // 8 loads for NEXT tile: stay in flight
      asm volatile("s_waitcnt vmcnt(8)" ::: "memory");  // current tile landed
    } else {
      asm volatile("s_waitcnt vmcnt(0)" ::: "memory");
    }
    __builtin_amdgcn_s_barrier();        // all waves' portions landed
    __builtin_amdgcn_sched_barrier(0);   // no LDS read above the barrier

    const us_t* Ab = &As[buf][0];
    const us_t* Bb = &Bs[buf][0];
    half8 a0[4], a1[4], b0[4], b1[4];
#pragma unroll
    for (int im = 0; im < 4; ++im) {
      a0[im] = *(const half8*)(Ab + ra + im * 1024 + s0);
      a1[im] = *(const half8*)(Ab + ra + im * 1024 + s1);
    }
#pragma unroll
    for (int in = 0; in < 4; ++in) {
      b0[in] = *(const half8*)(Bb + rb + in * 1024 + s0);
      b1[in] = *(const half8*)(Bb + rb + in * 1024 + s1);
    }
    __builtin_amdgcn_s_setprio(1);
#pragma unroll
    for (int in = 0; in < 4; ++in)
#pragma unroll
      for (int im = 0; im < 4; ++im)
        acc[im][in] = __builtin_amdgcn_mfma_f32_16x16x32_f16(a0[im], b0[in], acc[im][in], 0, 0, 0);
#pragma unroll
    for (int in = 0; in < 4; ++in)
#pragma unroll
      for (int im = 0; im < 4; ++im)
        acc[im][in] = __builtin_amdgcn_mfma_f32_16x16x32_f16(a1[im], b1[in], acc[im][in], 0, 0, 0);
    __builtin_amdgcn_s_setprio(0);
    __builtin_amdgcn_sched_barrier(0);   // reads consumed; no MFMA sink below
    __builtin_amdgcn_s_barrier();        // all waves done reading buf
  }
#undef STAGE8

#pragma unroll
  for (int in = 0; in < 4; ++in) {
    const int col = n0 + wn + in * 16 + r;
    const float bv = Bias[col];
#pragma unroll
    for (int im = 0; im < 4; ++im) {
      const int row = m0 + wm + im * 16 + q * 4;
#pragma unroll
      for (int i = 0; i < 4; ++i)
        C[(size_t)(row + i) * NOUT + col] = acc[im][in][i] + bv;
    }
  }
}

// ---------------- fallback GEMM (f32 staging, round-4 verified) ----------------
__global__ __launch_bounds__(256) void gemm_bias(const float* __restrict__ X,
                                                 const float* __restrict__ W,
                                                 const float* __restrict__ Bias,
                                                 float* __restrict__ C) {
  __shared__ __attribute__((aligned(16))) us_t As[128 * 32];
  __shared__ __attribute__((aligned(16))) us_t Bs[128 * 32];
  const int t = threadIdx.x;
  const int m0 = blockIdx.y * 128, n0 = blockIdx.x * 128;
  const int l = t & 63, w = t >> 6;
  const int r = l & 15, q = l >> 4;
  const int wm = (w >> 1) * 64, wn = (w & 1) * 64;
  const float* Ag = X + (size_t)(m0 + (t >> 2)) * DIN + (t & 3) * 8;
  const float* Bg = W + (size_t)(n0 + (t >> 2)) * DIN + (t & 3) * 8;
  us_t* la = As + t * 8;
  us_t* lb = Bs + t * 8;
  floatx4 acc[4][4] = {};
  const us_t* pa = As + (wm + r) * 32 + q * 8;
  const us_t* pb = Bs + (wn + r) * 32 + q * 8;
  for (int kt = 0; kt < DIN; kt += 32) {
    float4 a0 = *(const float4*)(Ag + kt);
    float4 a1 = *(const float4*)(Ag + kt + 4);
    float4 a2 = *(const float4*)(Ag + kt + 64 * DIN);
    float4 a3 = *(const float4*)(Ag + kt + 64 * DIN + 4);
    float4 b0 = *(const float4*)(Bg + kt);
    float4 b1 = *(const float4*)(Bg + kt + 4);
    float4 b2 = *(const float4*)(Bg + kt + 64 * DIN);
    float4 b3 = *(const float4*)(Bg + kt + 64 * DIN + 4);
    uint4 ua  = {pk2(a0.x, a0.y), pk2(a0.z, a0.w), pk2(a1.x, a1.y), pk2(a1.z, a1.w)};
    uint4 ua2 = {pk2(a2.x, a2.y), pk2(a2.z, a2.w), pk2(a3.x, a3.y), pk2(a3.z, a3.w)};
    uint4 ub  = {pk2(b0.x, b0.y), pk2(b0.z, b0.w), pk2(b1.x, b1.y), pk2(b1.z, b1.w)};
    uint4 ub2 = {pk2(b2.x, b2.y), pk2(b2.z, b2.w), pk2(b3.x, b3.y), pk2(b3.z, b3.w)};
    *(uint4*)la = ua;
    *(uint4*)(la + 2048) = ua2;
    *(uint4*)lb = ub;
    *(uint4*)(lb + 2048) = ub2;
    __syncthreads();
    half8 af[4];
#pragma unroll
    for (int im = 0; im < 4; ++im)
      af[im] = *(const half8*)(pa + im * 16 * 32);
#pragma unroll
    for (int in = 0; in < 4; ++in) {
      half8 bfv = *(const half8*)(pb + in * 16 * 32);
#pragma unroll
      for (int im = 0; im < 4; ++im)
        acc[im][in] = __builtin_amdgcn_mfma_f32_16x16x32_f16(af[im], bfv, acc[im][in], 0, 0, 0);
    }
    __syncthreads();
  }
#pragma unroll
  for (int in = 0; in < 4; ++in) {
    const int col = n0 + wn + in * 16 + r;
    const float bv = Bias[col];
#pragma unroll
    for (int im = 0; im < 4; ++im) {
      const int row = m0 + wm + im * 16 + q * 4;
#pragma unroll
      for (int i = 0; i < 4; ++i)
        C[(size_t)(row + i) * NOUT + col] = acc[im][in][i] + bv;
    }
  }
}

// ---------------- per-row exact top-KTOK membership -> counts ----------------
// Round-3: the three serial t==0 threshold scans (each ~256 dependent LDS
// reads at ~120cy) replaced by a 256-thread Hillis-Steele suffix scan +
// unique boundary-thread selection. Arithmetic identical.
__global__ __launch_bounds__(256) void row_topk(const float* __restrict__ TV,
                                                int* __restrict__ counts) {
  __shared__ __attribute__((aligned(16))) unsigned keys[NOUT];
  __shared__ int hist[2048];
  __shared__ int csum[256];
  __shared__ int shv[2];
  __shared__ int cnte[NCHUNK * 4];
  const int t = threadIdx.x;
  const int lane = t & 63, wv = t >> 6;

  for (int i = t; i < 2048; i += 256) hist[i] = 0;
  __syncthreads();
  // fused: load + key + pass-A histogram (bits [31:21])
  const uint4* src = (const uint4*)(TV + (size_t)blockIdx.x * NOUT);
  for (int i = t; i < NOUT / 4; i += 256) {
    uint4 v = src[i];
    unsigned k0 = fkey32(v.x), k1 = fkey32(v.y), k2 = fkey32(v.z), k3 = fkey32(v.w);
    uint4 kk = {k0, k1, k2, k3};
    *(uint4*)&keys[i * 4] = kk;
    atomicAdd(&hist[k0 >> 21], 1);
    atomicAdd(&hist[k1 >> 21], 1);
    atomicAdd(&hist[k2 >> 21], 1);
    atomicAdd(&hist[k3 >> 21], 1);
  }
  __syncthreads();
  { int s = 0; for (int j = 0; j < 8; ++j) s += hist[t * 8 + j]; csum[t] = s; }
  __syncthreads();
  // parallel suffix scan: csum[t] -> inclusive suffix sum
  for (int off = 1; off < 256; off <<= 1) {
    int u = (t + off < 256) ? csum[t + off] : 0;
    __syncthreads();
    csum[t] += u;
    __syncthreads();
  }
  {
    const bool c0 = csum[t] >= KTOK;
    const bool c1 = (t < 255) && (csum[t + 1] >= KTOK);
    if (c0 && !c1) {  // unique boundary thread (suffix sums non-increasing)
      int cum = (t < 255) ? csum[t + 1] : 0;
      for (int v = t * 8 + 7; v >= t * 8; --v) {
        if (cum + hist[v] >= KTOK) { shv[0] = v; shv[1] = cum; break; }
        cum += hist[v];
      }
    }
  }
  __syncthreads();
  const unsigned b1 = (unsigned)shv[0];
  const int above1 = shv[1];
  __syncthreads();

  // pass B: bits [20:10] among prefix==b1
  for (int i = t; i < 2048; i += 256) hist[i] = 0;
  __syncthreads();
  for (int i = t; i < NOUT; i += 256) {
    unsigned k = keys[i];
    if ((k >> 21) == b1) atomicAdd(&hist[(k >> 10) & 0x7FF], 1);
  }
  __syncthreads();
  { int s = 0; for (int j = 0; j < 8; ++j) s += hist[t * 8 + j]; csum[t] = s; }
  __syncthreads();
  for (int off = 1; off < 256; off <<= 1) {
    int u = (t + off < 256) ? csum[t + off] : 0;
    __syncthreads();
    csum[t] += u;
    __syncthreads();
  }
  {
    const bool c0 = above1 + csum[t] >= KTOK;
    const bool c1 = (t < 255) && (above1 + csum[t + 1] >= KTOK);
    if (c0 && !c1) {
      int cum = above1 + ((t < 255) ? csum[t + 1] : 0);
      for (int v = t * 8 + 7; v >= t * 8; --v) {
        if (cum + hist[v] >= KTOK) { shv[0] = v; shv[1] = cum; break; }
        cum += hist[v];
      }
    }
  }
  __syncthreads();
  const unsigned b2 = (unsigned)shv[0];
  const int above2 = shv[1];
  const unsigned pref2 = (b1 << 11) | b2;
  __syncthreads();

  // pass C: bits [9:0] among prefix==pref2
  for (int i = t; i < 1024; i += 256) hist[i] = 0;
  __syncthreads();
  for (int i = t; i < NOUT; i += 256) {
    unsigned k = keys[i];
    if ((k >> 10) == pref2) atomicAdd(&hist[k & 0x3FF], 1);
  }
  __syncthreads();
  { int s = 0; if (t < 128) { for (int j = 0; j < 8; ++j) s += hist[t * 8 + j]; } csum[t] = s; }
  __syncthreads();
  for (int off = 1; off < 256; off <<= 1) {
    int u = (t + off < 256) ? csum[t + off] : 0;
    __syncthreads();
    csum[t] += u;
    __syncthreads();
  }
  {
    const bool c0 = above2 + csum[t] >= KTOK;
    const bool c1 = (t < 255) && (above2 + csum[t + 1] >= KTOK);
    if (c0 && !c1) {  // boundary lands at t<128 (csum[t>=128]==0)
      int cum = above2 + ((t < 255) ? csum[t + 1] : 0);
      for (int v = t * 8 + 7; v >= t * 8; --v) {
        if (cum + hist[v] >= KTOK) { shv[0] = v; shv[1] = cum; break; }
        cum += hist[v];
      }
    }
  }
  __syncthreads();
  const unsigned T = (pref2 << 10) | (unsigned)shv[0];
  const int need = KTOK - shv[1];  // ties at T: ascending index order

  // membership sweep 1 (barrier-free): gt adds + per-(chunk,wave) eq counts
  for (int c = 0; c < NCHUNK; ++c) {
    const int i = c * 256 + t;
    const unsigned k = keys[i];
    if (k > T) atomicAdd(&counts[i], 1);
    unsigned long long me = __ballot(k == T);
    if (lane == 0) cnte[c * 4 + wv] = __popcll(me);
  }
  __syncthreads();
  // sweep 2: eq-rank resolution (eq elements rare; prefix computed on demand)
  for (int c = 0; c < NCHUNK; ++c) {
    const int i = c * 256 + t;
    const unsigned k = keys[i];
    const bool eq = (k == T);
    unsigned long long me = __ballot(eq);
    if (eq) {
      int rank = __popcll(me & ((1ULL << lane) - 1));
      const int idx = c * 4 + wv;
      for (int j = 0; j < idx; ++j) rank += cnte[j];
      if (rank < need) atomicAdd(&counts[i], 1);
    }
  }
}

// ---------------- top-NCORE of counts (ties: lower index), emit in index order --------
__global__ __launch_bounds__(256) void select_core(const int* __restrict__ counts,
                                                   const float* __restrict__ Bias,
                                                   int* __restrict__ core_idx,
                                                   float* __restrict__ bias_out) {
  __shared__ int cl[NOUT];
  __shared__ int hist[2049];
  __shared__ int csum[257];
  __shared__ int shv[2];
  __shared__ int tabS[256];  // packed (gt | eq<<16) per (chunk,wave)
  const int t = threadIdx.x;
  const int lane = t & 63, wv = t >> 6;
  for (int i = t; i < NOUT; i += 256) cl[i] = counts[i];
  for (int i = t; i < 2049; i += 256) hist[i] = 0;
  tabS[t] = 0;
  __syncthreads();
  for (int i = t; i < NOUT; i += 256) atomicAdd(&hist[cl[i]], 1);
  __syncthreads();
  { int s = 0; for (int j = 0; j < 8; ++j) s += hist[t * 8 + j]; csum[t] = s;
    if (t == 0) csum[256] = hist[2048]; }
  __syncthreads();
  if (t == 0) {
    int cum = 0;
    for (int c = 256; c >= 0; --c) {
      if (cum + csum[c] >= NCORE) {
        int hi = (c == 256) ? 2048 : c * 8 + 7;
        for (int v = hi; v >= c * 8; --v) {
          if (cum + hist[v] >= NCORE) { shv[0] = v; shv[1] = NCORE - cum; break; }
          cum += hist[v];
        }
        break;
      }
      cum += csum[c];
    }
  }
  __syncthreads();
  const int Cv = shv[0], need2 = shv[1];
  // sweep 1: per-(chunk,wave) ballot counts (no barriers)
  for (int c = 0; c < NCHUNK; ++c) {
    const int i = c * 256 + t;
    const int cnt = cl[i];
    unsigned long long mg = __ballot(cnt > Cv);
    unsigned long long me = __ballot(cnt == Cv);
    if (lane == 0) tabS[c * 4 + wv] = __popcll(mg) | (__popcll(me) << 16);
  }
  __syncthreads();
  // packed inclusive Hillis-Steele scan -> exclusive prefix
  int orig = tabS[t];
  for (int off = 1; off < 256; off <<= 1) {
    int v = (t >= off) ? tabS[t - off] : 0;
    __syncthreads();
    tabS[t] += v;
    __syncthreads();
  }
  int excl = tabS[t] - orig;
  __syncthreads();
  tabS[t] = excl;
  __syncthreads();
  // sweep 2: compute position, emit
  const unsigned long long lm = (1ULL << lane) - 1;
  for (int c = 0; c < NCHUNK; ++c) {
    const int i = c * 256 + t;
    const int cnt = cl[i];
    const bool g = cnt > Cv, e = cnt == Cv;
    unsigned long long mg = __ballot(g);
    unsigned long long me = __ballot(e);
    const int P = tabS[c * 4 + wv];
    const int gpre = (P & 0xFFFF) + __popcll(mg & lm);
    const int epre = (P >> 16) + __popcll(me & lm);
    const bool sel = g || (e && epre < need2);
    if (sel) {
      const int pos = gpre + (epre < need2 ? epre : need2);
      core_idx[pos] = i;
      bias_out[pos] = Bias[i];
    }
  }
}

// ---------------- gather selected weight rows (f32) ----------------
__global__ __launch_bounds__(256) void gather_rows(const float* __restrict__ W,
                                                   const int* __restrict__ core_idx,
                                                   float* __restrict__ outW) {
  const int b = blockIdx.x;
  const int j = core_idx[b];
  const float4* src = (const float4*)(W + (size_t)j * DIN);
  float4* dst = (float4*)(outW + (size_t)b * DIN);
  for (int i = threadIdx.x; i < DIN / 4; i += 256) dst[i] = src[i];
}

__global__ __launch_bounds__(256) void zero_counts(int* __restrict__ counts) {
  counts[blockIdx.x * 256 + threadIdx.x] = 0;
}

extern "C" void kernel_launch(void* const* d_in, const int* in_sizes, int n_in,
                              void* d_out, int out_size, void* d_ws, size_t ws_size,
                              hipStream_t stream) {
  const float* X    = (const float*)d_in[0];
  const float* W    = (const float*)d_in[1];
  const float* Bias = (const float*)d_in[2];
  float* out_tv = (float*)d_out;
  float* out_w  = out_tv + (size_t)SEQ * NOUT;
  float* out_b  = out_w + (size_t)NCORE * DIN;
  int* counts   = (int*)d_ws;
  int* core_idx = counts + NOUT;

  const size_t meta = 64 * 1024;
  const size_t need_ws = meta + ((size_t)SEQ * DIN + (size_t)NOUT * DIN) * sizeof(us_t);

  zero_counts<<<NOUT / 256, 256, 0, stream>>>(counts);
  if (ws_size >= need_ws) {
    us_t* X16 = (us_t*)((char*)d_ws + meta);
    us_t* W16 = X16 + (size_t)SEQ * DIN;
    cvt_f16<<<(SEQ * DIN / 8 + 255) / 256, 256, 0, stream>>>(X, (unsigned*)X16, SEQ * DIN / 8);
    cvt_f16<<<(NOUT * DIN / 8 + 255) / 256, 256, 0, stream>>>(W, (unsigned*)W16, NOUT * DIN / 8);
    gemm_f16<<<NBLK, 256, 0, stream>>>(X16, W16, Bias, out_tv);
  } else {
    gemm_bias<<<dim3(NOUT / 128, SEQ / 128), 256, 0, stream>>>(X, W, Bias, out_tv);
  }
  row_topk<<<SEQ, 256, 0, stream>>>(out_tv, counts);
  select_core<<<1, 256, 0, stream>>>(counts, Bias, core_idx, out_b);
  gather_rows<<<NCORE, 256, 0, stream>>>(W, core_idx, out_w);
}

// Round 4
// 681.735 us; speedup vs baseline: 1.2508x; 1.0970x over previous
//
#include <hip/hip_runtime.h>

typedef __attribute__((ext_vector_type(8))) _Float16 half8;
typedef __attribute__((ext_vector_type(4))) float floatx4;
typedef unsigned short us_t;

#define SEQ   2048
#define DIN   4096
#define NOUT  11008
#define KTOK  2201
#define NCORE 4403
#define NCHUNK 43   /* NOUT / 256 */
#define NT2   512   /* row_topk threads */
#define NCH2  22    /* ceil(NOUT / NT2) */
#define NBLK  1376  /* (NOUT/128) * (SEQ/128) = 86 * 16, divisible by 8 XCDs */

__device__ __forceinline__ unsigned pk2(float a, float b) {
  auto h = __builtin_amdgcn_cvt_pkrtz(a, b);  // exact: values are f16-origin
  return __builtin_bit_cast(unsigned, h);
}
// monotone map: f32 bits -> ascending-ordered u32 key
__device__ __forceinline__ unsigned fkey32(unsigned u) {
  return u ^ ((u >> 31) ? 0xFFFFFFFFu : 0x80000000u);
}
__device__ __forceinline__ void gl2lds16(const us_t* g, us_t* l) {
  __builtin_amdgcn_global_load_lds(
      (const __attribute__((address_space(1))) unsigned int*)(g),
      (__attribute__((address_space(3))) unsigned int*)(l), 16, 0, 0);
}

// Kogge-Stone inclusive SUFFIX sum within a 64-lane wave (registers only).
__device__ __forceinline__ int wave_suffix_incl(int x, int lane) {
#pragma unroll
  for (int off = 1; off < 64; off <<= 1) {
    int y = __shfl_down(x, off);
    x += (lane + off < 64) ? y : 0;
  }
  return x;  // lane l holds sum over lanes l..63
}

// Parallel threshold-find over (NW*64*G) descending-significance bins.
// Stores: shv[0] = chosen bin, shv[1] = count strictly above chosen bin.
template <int G, int NW>
__device__ __forceinline__ void find_thr(const int* hist, int above, int K,
                                         int* wtot, int* shv,
                                         int t, int lane, int wv) {
  int val = 0;
#pragma unroll
  for (int j = 0; j < G; ++j) val += hist[t * G + j];
  int x = wave_suffix_incl(val, lane);
  if (lane == 0) wtot[wv] = x;
  __syncthreads();
  int add = 0;
#pragma unroll
  for (int w2 = 0; w2 < NW; ++w2) add += (w2 > wv) ? wtot[w2] : 0;
  const int suf = x + add;       // suffix sum from group t (inclusive)
  const int sufn = suf - val;    // suffix sum from group t+1
  if (above + suf >= K && above + sufn < K) {  // unique boundary thread
    int cum = above + sufn;
    for (int v = t * G + G - 1; v >= t * G; --v) {
      if (cum + hist[v] >= K) { shv[0] = v; shv[1] = cum; break; }
      cum += hist[v];
    }
  }
  __syncthreads();
}

// ---------------- f32 -> f16 conversion (8 elems/thread) ----------------
__global__ __launch_bounds__(256) void cvt_f16(const float* __restrict__ src,
                                               unsigned* __restrict__ dst, int n8) {
  int i = blockIdx.x * 256 + threadIdx.x;
  if (i >= n8) return;
  const float4* s = (const float4*)src + (size_t)i * 2;
  float4 a = s[0], b = s[1];
  uint4 o = {pk2(a.x, a.y), pk2(a.z, a.w), pk2(b.x, b.y), pk2(b.z, b.w)};
  ((uint4*)dst)[i] = o;
}

// ---------------- fast GEMM: f16 inputs via global_load_lds (m97 structure) ----------
// Round-2 verified version (245us): 1D grid, n-major block order + bijective
// XCD-chunk swizzle (co-resident blocks share W panels; FETCH 874->184MB).
// Round-1/3 pipeline grafts (counted vmcnt, BK=64 dbuf, T2 swizzle) both
// REGRESSED per the 2-phase regime gate -> structure frozen at 2-phase.
__global__ __launch_bounds__(256) void gemm_f16(const us_t* __restrict__ X16,
                                                const us_t* __restrict__ W16,
                                                const float* __restrict__ Bias,
                                                float* __restrict__ C) {
  __shared__ __attribute__((aligned(16))) us_t As[128 * 32];
  __shared__ __attribute__((aligned(16))) us_t Bs[128 * 32];
  const int t = threadIdx.x;

  // bijective XCD-chunk swizzle (1376 = 8 * 172): id%8 -> XCD, each XCD
  // gets 172 consecutive wg of the n-major sequence.
  const int id = blockIdx.x;
  const int wg = ((id & 7) * (NBLK / 8)) + (id >> 3);
  const int n0 = (wg >> 4) * 128;  // n-major: column advances every 16 wg
  const int m0 = (wg & 15) * 128;  // 16 m-tiles of one column are consecutive

  const int l = t & 63, w = t >> 6;
  const int r = l & 15, q = l >> 4;
  const int wm = (w >> 1) * 64, wn = (w & 1) * 64;

  const us_t* Ag = X16 + (size_t)(m0 + (t >> 2)) * DIN + (t & 3) * 8;
  const us_t* Bg = W16 + (size_t)(n0 + (t >> 2)) * DIN + (t & 3) * 8;
  us_t* la = As + t * 8;
  us_t* lb = Bs + t * 8;

  floatx4 acc[4][4] = {};
  const us_t* pa = As + (wm + r) * 32 + q * 8;
  const us_t* pb = Bs + (wn + r) * 32 + q * 8;

  for (int kt = 0; kt < DIN; kt += 32) {
    gl2lds16(Ag + kt, la);
    gl2lds16(Ag + kt + 64 * DIN, la + 2048);
    gl2lds16(Bg + kt, lb);
    gl2lds16(Bg + kt + 64 * DIN, lb + 2048);
    __syncthreads();
    half8 af[4];
#pragma unroll
    for (int im = 0; im < 4; ++im)
      af[im] = *(const half8*)(pa + im * 16 * 32);
#pragma unroll
    for (int in = 0; in < 4; ++in) {
      half8 bfv = *(const half8*)(pb + in * 16 * 32);
#pragma unroll
      for (int im = 0; im < 4; ++im)
        acc[im][in] = __builtin_amdgcn_mfma_f32_16x16x32_f16(af[im], bfv, acc[im][in], 0, 0, 0);
    }
    __syncthreads();
  }
#pragma unroll
  for (int in = 0; in < 4; ++in) {
    const int col = n0 + wn + in * 16 + r;
    const float bv = Bias[col];
#pragma unroll
    for (int im = 0; im < 4; ++im) {
      const int row = m0 + wm + im * 16 + q * 4;
#pragma unroll
      for (int i = 0; i < 4; ++i)
        C[(size_t)(row + i) * NOUT + col] = acc[im][in][i] + bv;
    }
  }
}

// ---------------- fallback GEMM (f32 staging, round-4 verified) ----------------
__global__ __launch_bounds__(256) void gemm_bias(const float* __restrict__ X,
                                                 const float* __restrict__ W,
                                                 const float* __restrict__ Bias,
                                                 float* __restrict__ C) {
  __shared__ __attribute__((aligned(16))) us_t As[128 * 32];
  __shared__ __attribute__((aligned(16))) us_t Bs[128 * 32];
  const int t = threadIdx.x;
  const int m0 = blockIdx.y * 128, n0 = blockIdx.x * 128;
  const int l = t & 63, w = t >> 6;
  const int r = l & 15, q = l >> 4;
  const int wm = (w >> 1) * 64, wn = (w & 1) * 64;
  const float* Ag = X + (size_t)(m0 + (t >> 2)) * DIN + (t & 3) * 8;
  const float* Bg = W + (size_t)(n0 + (t >> 2)) * DIN + (t & 3) * 8;
  us_t* la = As + t * 8;
  us_t* lb = Bs + t * 8;
  floatx4 acc[4][4] = {};
  const us_t* pa = As + (wm + r) * 32 + q * 8;
  const us_t* pb = Bs + (wn + r) * 32 + q * 8;
  for (int kt = 0; kt < DIN; kt += 32) {
    float4 a0 = *(const float4*)(Ag + kt);
    float4 a1 = *(const float4*)(Ag + kt + 4);
    float4 a2 = *(const float4*)(Ag + kt + 64 * DIN);
    float4 a3 = *(const float4*)(Ag + kt + 64 * DIN + 4);
    float4 b0 = *(const float4*)(Bg + kt);
    float4 b1 = *(const float4*)(Bg + kt + 4);
    float4 b2 = *(const float4*)(Bg + kt + 64 * DIN);
    float4 b3 = *(const float4*)(Bg + kt + 64 * DIN + 4);
    uint4 ua  = {pk2(a0.x, a0.y), pk2(a0.z, a0.w), pk2(a1.x, a1.y), pk2(a1.z, a1.w)};
    uint4 ua2 = {pk2(a2.x, a2.y), pk2(a2.z, a2.w), pk2(a3.x, a3.y), pk2(a3.z, a3.w)};
    uint4 ub  = {pk2(b0.x, b0.y), pk2(b0.z, b0.w), pk2(b1.x, b1.y), pk2(b1.z, b1.w)};
    uint4 ub2 = {pk2(b2.x, b2.y), pk2(b2.z, b2.w), pk2(b3.x, b3.y), pk2(b3.z, b3.w)};
    *(uint4*)la = ua;
    *(uint4*)(la + 2048) = ua2;
    *(uint4*)lb = ub;
    *(uint4*)(lb + 2048) = ub2;
    __syncthreads();
    half8 af[4];
#pragma unroll
    for (int im = 0; im < 4; ++im)
      af[im] = *(const half8*)(pa + im * 16 * 32);
#pragma unroll
    for (int in = 0; in < 4; ++in) {
      half8 bfv = *(const half8*)(pb + in * 16 * 32);
#pragma unroll
      for (int im = 0; im < 4; ++im)
        acc[im][in] = __builtin_amdgcn_mfma_f32_16x16x32_f16(af[im], bfv, acc[im][in], 0, 0, 0);
    }
    __syncthreads();
  }
#pragma unroll
  for (int in = 0; in < 4; ++in) {
    const int col = n0 + wn + in * 16 + r;
    const float bv = Bias[col];
#pragma unroll
    for (int im = 0; im < 4; ++im) {
      const int row = m0 + wm + im * 16 + q * 4;
#pragma unroll
      for (int i = 0; i < 4; ++i)
        C[(size_t)(row + i) * NOUT + col] = acc[im][in][i] + bv;
    }
  }
}

// ---------------- per-row exact top-KTOK membership -> counts ----------------
// Round-4: 512 threads (24 waves/CU at 3 blocks/CU vs 12 before) + register
// shfl suffix-scans for all three threshold finds (2 barriers each vs 16).
// Selection arithmetic identical to the verified radix-refinement scheme.
__global__ __launch_bounds__(NT2) void row_topk(const float* __restrict__ TV,
                                                int* __restrict__ counts) {
  __shared__ __attribute__((aligned(16))) unsigned keys[NOUT];
  __shared__ int hist[2048];
  __shared__ int wtot[NT2 / 64];
  __shared__ int shv[2];
  __shared__ int cnte[NCH2 * (NT2 / 64)];
  const int t = threadIdx.x;
  const int lane = t & 63, wv = t >> 6;

  for (int i = t; i < 2048; i += NT2) hist[i] = 0;
  __syncthreads();
  // fused: load + key + pass-A histogram (bits [31:21])
  const uint4* src = (const uint4*)(TV + (size_t)blockIdx.x * NOUT);
  for (int i = t; i < NOUT / 4; i += NT2) {
    uint4 v = src[i];
    unsigned k0 = fkey32(v.x), k1 = fkey32(v.y), k2 = fkey32(v.z), k3 = fkey32(v.w);
    uint4 kk = {k0, k1, k2, k3};
    *(uint4*)&keys[i * 4] = kk;
    atomicAdd(&hist[k0 >> 21], 1);
    atomicAdd(&hist[k1 >> 21], 1);
    atomicAdd(&hist[k2 >> 21], 1);
    atomicAdd(&hist[k3 >> 21], 1);
  }
  __syncthreads();
  find_thr<4, NT2 / 64>(hist, 0, KTOK, wtot, shv, t, lane, wv);
  const unsigned b1 = (unsigned)shv[0];
  const int above1 = shv[1];
  __syncthreads();

  // pass B: bits [20:10] among prefix==b1
  for (int i = t; i < 2048; i += NT2) hist[i] = 0;
  __syncthreads();
  for (int i = t; i < NOUT; i += NT2) {
    unsigned k = keys[i];
    if ((k >> 21) == b1) atomicAdd(&hist[(k >> 10) & 0x7FF], 1);
  }
  __syncthreads();
  find_thr<4, NT2 / 64>(hist, above1, KTOK, wtot, shv, t, lane, wv);
  const unsigned b2 = (unsigned)shv[0];
  const int above2 = shv[1];
  const unsigned pref2 = (b1 << 11) | b2;
  __syncthreads();

  // pass C: bits [9:0] among prefix==pref2
  for (int i = t; i < 1024; i += NT2) hist[i] = 0;
  __syncthreads();
  for (int i = t; i < NOUT; i += NT2) {
    unsigned k = keys[i];
    if ((k >> 10) == pref2) atomicAdd(&hist[k & 0x3FF], 1);
  }
  __syncthreads();
  find_thr<2, NT2 / 64>(hist, above2, KTOK, wtot, shv, t, lane, wv);
  const unsigned T = (pref2 << 10) | (unsigned)shv[0];
  const int need = KTOK - shv[1];  // ties at T: ascending index order

  // membership sweep 1 (barrier-free): gt adds + per-(chunk,wave) eq counts
  for (int c = 0; c < NCH2; ++c) {
    const int i = c * NT2 + t;
    const bool valid = i < NOUT;
    const unsigned k = valid ? keys[i] : 0u;
    if (valid && k > T) atomicAdd(&counts[i], 1);
    unsigned long long me = __ballot(valid && (k == T));
    if (lane == 0) cnte[c * (NT2 / 64) + wv] = __popcll(me);
  }
  __syncthreads();
  // sweep 2: eq-rank resolution (eq elements rare; prefix computed on demand)
  for (int c = 0; c < NCH2; ++c) {
    const int i = c * NT2 + t;
    const bool valid = i < NOUT;
    const unsigned k = valid ? keys[i] : 0u;
    const bool eq = valid && (k == T);
    unsigned long long me = __ballot(eq);
    if (eq) {
      int rank = __popcll(me & ((1ULL << lane) - 1));
      const int idx = c * (NT2 / 64) + wv;
      for (int j = 0; j < idx; ++j) rank += cnte[j];
      if (rank < need) atomicAdd(&counts[i], 1);
    }
  }
}

// ---------------- top-NCORE of counts (ties: lower index), emit in index order --------
// Round-4 (single-block kernel, makespan-critical): serial t==0 threshold
// scan -> register suffix-scan; packed LDS Hillis-Steele -> shfl prefix scan.
__global__ __launch_bounds__(256) void select_core(const int* __restrict__ counts,
                                                   const float* __restrict__ Bias,
                                                   int* __restrict__ core_idx,
                                                   float* __restrict__ bias_out) {
  __shared__ int cl[NOUT];
  __shared__ int hist[2049];
  __shared__ int wtot[4];
  __shared__ int shv[2];
  __shared__ int tabS[256];  // packed (gt | eq<<16) per (chunk,wave)
  const int t = threadIdx.x;
  const int lane = t & 63, wv = t >> 6;
  for (int i = t; i < NOUT; i += 256) cl[i] = counts[i];
  for (int i = t; i < 2049; i += 256) hist[i] = 0;
  __syncthreads();
  for (int i = t; i < NOUT; i += 256) atomicAdd(&hist[cl[i]], 1);
  __syncthreads();
  // threshold find over 2049 bins; bin 2048 folded into thread 255's group
  // (scanned first there, preserving descending bin order).
  {
    int val = 0;
#pragma unroll
    for (int j = 0; j < 8; ++j) val += hist[t * 8 + j];
    if (t == 255) val += hist[2048];
    int x = wave_suffix_incl(val, lane);
    if (lane == 0) wtot[wv] = x;
    __syncthreads();
    int add = 0;
#pragma unroll
    for (int w2 = 0; w2 < 4; ++w2) add += (w2 > wv) ? wtot[w2] : 0;
    const int suf = x + add;
    const int sufn = suf - val;
    if (suf >= NCORE && sufn < NCORE) {
      int cum = sufn;
      const int hi = (t == 255) ? 2048 : t * 8 + 7;
      for (int v = hi; v >= t * 8; --v) {
        if (cum + hist[v] >= NCORE) { shv[0] = v; shv[1] = NCORE - cum; break; }
        cum += hist[v];
      }
    }
    __syncthreads();
  }
  const int Cv = shv[0], need2 = shv[1];
  // sweep 1: per-(chunk,wave) ballot counts (no barriers)
  for (int c = 0; c < NCHUNK; ++c) {
    const int i = c * 256 + t;
    const int cnt = cl[i];
    unsigned long long mg = __ballot(cnt > Cv);
    unsigned long long me = __ballot(cnt == Cv);
    if (lane == 0) tabS[c * 4 + wv] = __popcll(mg) | (__popcll(me) << 16);
    else if (c == 0) tabS[c * 4 + wv] = tabS[c * 4 + wv];  // no-op keep shape
  }
  // entries beyond NCHUNK*4 = 172 must be zero for the scan
  if (t >= NCHUNK * 4) tabS[t] = 0;
  __syncthreads();
  // packed exclusive prefix via register shfl scan (fields < 2^16, no carry)
  {
    const int orig = tabS[t];
    int x = orig;
#pragma unroll
    for (int off = 1; off < 64; off <<= 1) {
      int y = __shfl_up(x, off);
      x += (lane >= off) ? y : 0;
    }
    if (lane == 63) wtot[wv] = x;
    __syncthreads();
    int add = 0;
#pragma unroll
    for (int w2 = 0; w2 < 4; ++w2) add += (w2 < wv) ? wtot[w2] : 0;
    const int excl = x - orig + add;
    __syncthreads();
    tabS[t] = excl;
    __syncthreads();
  }
  // sweep 2: compute position, emit
  const unsigned long long lm = (1ULL << lane) - 1;
  for (int c = 0; c < NCHUNK; ++c) {
    const int i = c * 256 + t;
    const int cnt = cl[i];
    const bool g = cnt > Cv, e = cnt == Cv;
    unsigned long long mg = __ballot(g);
    unsigned long long me = __ballot(e);
    const int P = tabS[c * 4 + wv];
    const int gpre = (P & 0xFFFF) + __popcll(mg & lm);
    const int epre = (P >> 16) + __popcll(me & lm);
    const bool sel = g || (e && epre < need2);
    if (sel) {
      const int pos = gpre + (epre < need2 ? epre : need2);
      core_idx[pos] = i;
      bias_out[pos] = Bias[i];
    }
  }
}

// ---------------- gather selected weight rows (f16 source, exact) ----------------
__global__ __launch_bounds__(256) void gather_rows16(const us_t* __restrict__ W16,
                                                     const int* __restrict__ core_idx,
                                                     float* __restrict__ outW) {
  const int b = blockIdx.x;
  const int j = core_idx[b];
  const half8* src = (const half8*)(W16 + (size_t)j * DIN);
  float4* dst = (float4*)(outW + (size_t)b * DIN);
  for (int i = threadIdx.x; i < DIN / 8; i += 256) {
    half8 h = src[i];
    float4 lo = {(float)h[0], (float)h[1], (float)h[2], (float)h[3]};
    float4 hi = {(float)h[4], (float)h[5], (float)h[6], (float)h[7]};
    dst[i * 2] = lo;
    dst[i * 2 + 1] = hi;
  }
}

// f32-source fallback gather
__global__ __launch_bounds__(256) void gather_rows(const float* __restrict__ W,
                                                   const int* __restrict__ core_idx,
                                                   float* __restrict__ outW) {
  const int b = blockIdx.x;
  const int j = core_idx[b];
  const float4* src = (const float4*)(W + (size_t)j * DIN);
  float4* dst = (float4*)(outW + (size_t)b * DIN);
  for (int i = threadIdx.x; i < DIN / 4; i += 256) dst[i] = src[i];
}

__global__ __launch_bounds__(256) void zero_counts(int* __restrict__ counts) {
  counts[blockIdx.x * 256 + threadIdx.x] = 0;
}

extern "C" void kernel_launch(void* const* d_in, const int* in_sizes, int n_in,
                              void* d_out, int out_size, void* d_ws, size_t ws_size,
                              hipStream_t stream) {
  const float* X    = (const float*)d_in[0];
  const float* W    = (const float*)d_in[1];
  const float* Bias = (const float*)d_in[2];
  float* out_tv = (float*)d_out;
  float* out_w  = out_tv + (size_t)SEQ * NOUT;
  float* out_b  = out_w + (size_t)NCORE * DIN;
  int* counts   = (int*)d_ws;
  int* core_idx = counts + NOUT;

  const size_t meta = 64 * 1024;
  const size_t need_ws = meta + ((size_t)SEQ * DIN + (size_t)NOUT * DIN) * sizeof(us_t);

  zero_counts<<<NOUT / 256, 256, 0, stream>>>(counts);
  if (ws_size >= need_ws) {
    us_t* X16 = (us_t*)((char*)d_ws + meta);
    us_t* W16 = X16 + (size_t)SEQ * DIN;
    cvt_f16<<<(SEQ * DIN / 8 + 255) / 256, 256, 0, stream>>>(X, (unsigned*)X16, SEQ * DIN / 8);
    cvt_f16<<<(NOUT * DIN / 8 + 255) / 256, 256, 0, stream>>>(W, (unsigned*)W16, NOUT * DIN / 8);
    gemm_f16<<<NBLK, 256, 0, stream>>>(X16, W16, Bias, out_tv);
    row_topk<<<SEQ, NT2, 0, stream>>>(out_tv, counts);
    select_core<<<1, 256, 0, stream>>>(counts, Bias, core_idx, out_b);
    gather_rows16<<<NCORE, 256, 0, stream>>>(W16, core_idx, out_w);
  } else {
    gemm_bias<<<dim3(NOUT / 128, SEQ / 128), 256, 0, stream>>>(X, W, Bias, out_tv);
    row_topk<<<SEQ, NT2, 0, stream>>>(out_tv, counts);
    select_core<<<1, 256, 0, stream>>>(counts, Bias, core_idx, out_b);
    gather_rows<<<NCORE, 256, 0, stream>>>(W, core_idx, out_w);
  }
}